// Round 3
// baseline (180.849 us; speedup 1.0000x reference)
//
#include <hip/hip_runtime.h>
#include <math.h>

#define NATOMS 1536
#define NSPEC 8
#define HID 64
#define NCEN 32
#define CUTOFF_R 5.0f
#define PI_F 3.14159265358979323846f
#define NBR_CAP 1024   // max in-cutoff neighbors per atom (~560 worst case here)
#define PREP_BLOCKS 65
#define AP 8           // atoms per k_charge block
#define CHG_BLOCKS (NATOMS / AP)   // 192
#define PAIR_B 768     // k_tail: blocks 0..767 pair MLP, 768..1023 LR+charges
#define TAIL_GRID 1024

typedef __attribute__((ext_vector_type(8))) short short8;   // 8 bf16
typedef __attribute__((ext_vector_type(4))) float float4v;  // MFMA C/D

__device__ __forceinline__ float silu_f(float x) {
    return x / (1.f + __expf(-x));
}
__device__ __forceinline__ short f2bf(float x) {   // RNE f32->bf16
    unsigned u = __float_as_uint(x);
    u += 0x7fffu + ((u >> 16) & 1u);
    return (short)(u >> 16);
}
__device__ __forceinline__ float cut_f(float d) {
    return 0.5f * (__cosf((PI_F / CUTOFF_R) * d) + 1.f);
}

// ---------------------------------------------------------------------------
// K1 (R16) k_nbr: R13's proven phases 1/1b/2 (256t, exact summation order ->
// absmax ~1.5e-5), but phase 3 is REMOVED: the 289-float feature row is
// written to global xfeat instead. This is the ablation: R13/R15 showed wall
// time invariant to occupancy and serial-path halving (44-45us at 35% and
// 50% occ), so the ~30us beyond VALU-issue is phase-latency. Splitting gives
// separate rocprof rows for phases 1/2 vs the weight-streaming phase 3.
// Blocks [1536,1601): prep (ctab, bw1, bw2) unchanged.
// ---------------------------------------------------------------------------
__global__ __launch_bounds__(256) void k_nbr(
    const int* __restrict__ species, const float* __restrict__ pos,
    const float* __restrict__ tq, const float* __restrict__ embed,
    const float* __restrict__ W1, const float* __restrict__ b1,
    const float* __restrict__ W2,
    float* __restrict__ ctab, short* __restrict__ bw1, short* __restrict__ bw2,
    float* __restrict__ xfeat,
    unsigned int* __restrict__ pcount, uint2* __restrict__ pdlist)
{
    __shared__ float2 dc_l[NBR_CAP];            // 8 KB  (d, cut)
    __shared__ unsigned short spj_l[NBR_CAP];   // 2 KB  (species<<11 | j)
    __shared__ unsigned short pj_l[NBR_CAP];    // 2 KB  (neighbor-list index)
    __shared__ float s_part[8 * 256];           // 8 KB  (bucket partials)
    __shared__ unsigned n_cnt, p_cnt, s_base;

    const int t = threadIdx.x;

    // ---------------- prep blocks ----------------
    if (blockIdx.x >= NATOMS) {
        const int b = blockIdx.x - NATOMS;
        if (b < 64) {
            if (t < 64) {
                const int c = b;                  // combo = si*8+sj
                const int si2 = c >> 3, sj2 = c & 7;
                const int o = t;
                float acc = b1[o];
                #pragma unroll 4
                for (int k = 0; k < 32; k++) {
                    const float a = embed[si2 * 32 + k];
                    const float bb = embed[sj2 * 32 + k];
                    acc += (a + bb) * W1[(32 + k) * HID + o];
                    acc += (a * bb) * W1[(64 + k) * HID + o];
                }
                ctab[c * HID + o] = acc;
            }
        } else {
            for (int e = t; e < 2048; e += 256) {
                const int tile = e >> 9, L = (e >> 3) & 63, j = e & 7;
                const int k = (L >> 4) * 8 + j;
                const int n = tile * 16 + (L & 15);
                bw1[e] = f2bf(W1[k * HID + n]);
            }
            for (int e = t; e < 4096; e += 256) {
                const int ct = e >> 9, L = (e >> 3) & 63, j = e & 7;
                const int c = ct >> 2, tile = ct & 3;
                const int k = c * 32 + (L >> 4) * 8 + j;
                const int n = tile * 16 + (L & 15);
                bw2[e] = f2bf(W2[k * HID + n]);
            }
        }
        return;
    }

    const int i = blockIdx.x;
    const int lane = t & 63;
    if (t == 0) { n_cnt = 0u; p_cnt = 0u; }
    __syncthreads();

    const float xi = pos[3*i+0], yi = pos[3*i+1], zi = pos[3*i+2];
    const int si = species[i];

    // ---- phase 1: neighbor compaction ----
    #pragma unroll
    for (int j0 = 0; j0 < NATOMS; j0 += 256) {
        const int j = j0 + t;
        const float dx = xi - pos[3*j+0];
        const float dy = yi - pos[3*j+1];
        const float dz = zi - pos[3*j+2];
        const float d = sqrtf(dx*dx + dy*dy + dz*dz + 1e-12f);
        const bool within = (d < CUTOFF_R) && (j != i);
        const unsigned long long m = __ballot((int)within);
        if (within) {
            const unsigned prefix = (unsigned)__popcll(m & ((1ull << lane) - 1ull));
            unsigned base = 0;
            if (prefix == 0) base = atomicAdd(&n_cnt, (unsigned)__popcll(m));
            base = (unsigned)__builtin_amdgcn_readfirstlane((int)base);
            const unsigned ofs = base + prefix;
            if (ofs < NBR_CAP) {
                dc_l[ofs] = make_float2(d, cut_f(d));
                spj_l[ofs] = (unsigned short)((species[j] << 11) | j);
            }
        }
    }
    __syncthreads();
    const unsigned cnt = (n_cnt < NBR_CAP) ? n_cnt : NBR_CAP;

    // ---- phase 1b: pair list (j > i), store neighbor-list index ----
    for (unsigned n0 = 0; n0 < cnt; n0 += 256) {
        const unsigned n = n0 + (unsigned)t;
        bool app = false;
        if (n < cnt) app = ((int)(spj_l[n] & 2047u) > i);
        const unsigned long long m = __ballot((int)app);
        if (app) {
            const unsigned prefix = (unsigned)__popcll(m & ((1ull << lane) - 1ull));
            unsigned base = 0;
            if (prefix == 0) base = atomicAdd(&p_cnt, (unsigned)__popcll(m));
            base = (unsigned)__builtin_amdgcn_readfirstlane((int)base);
            pj_l[base + prefix] = (unsigned short)n;
        }
    }
    __syncthreads();
    if (t == 0) s_base = atomicAdd(pcount, p_cnt);
    __syncthreads();
    {
        const unsigned pc = p_cnt, base = s_base;
        for (unsigned idx = (unsigned)t; idx < pc; idx += 256) {
            const unsigned n = pj_l[idx];
            const unsigned w = spj_l[n];
            const unsigned jj = w & 2047u, spj = w >> 11;
            uint2 pd;
            pd.x = (((unsigned)si * 8u + spj) << 22) | ((unsigned)i << 11) | jj;
            pd.y = __float_as_uint(dc_l[n].x);
            pdlist[base + idx] = pd;
        }
    }

    // ---- phase 2: register-bucket basis accumulation (R8/R11-proven) ----
    {
        const int k = t & 31, gg = t >> 5;
        const float ck = (float)k * (CUTOFF_R / 31.f);
        float f0=0.f,f1=0.f,f2=0.f,f3=0.f,f4=0.f,f5=0.f,f6=0.f,f7=0.f;
        #pragma unroll 2
        for (unsigned n = (unsigned)gg; n < cnt; n += 8) {
            const float2 dc = dc_l[n];
            const float diff = dc.x - ck;
            const float v = __expf(-4.f * diff * diff) * dc.y;
            const int sp = (int)(spj_l[n] >> 11);
            f0 += (sp == 0) ? v : 0.f;
            f1 += (sp == 1) ? v : 0.f;
            f2 += (sp == 2) ? v : 0.f;
            f3 += (sp == 3) ? v : 0.f;
            f4 += (sp == 4) ? v : 0.f;
            f5 += (sp == 5) ? v : 0.f;
            f6 += (sp == 6) ? v : 0.f;
            f7 += (sp == 7) ? v : 0.f;
        }
        float* sp_g = &s_part[gg * 256 + k];
        sp_g[0*32] = f0; sp_g[1*32] = f1; sp_g[2*32] = f2; sp_g[3*32] = f3;
        sp_g[4*32] = f4; sp_g[5*32] = f5; sp_g[6*32] = f6; sp_g[7*32] = f7;
    }
    __syncthreads();
    {
        float acc = 0.f;
        #pragma unroll
        for (int g2 = 0; g2 < 8; g2++) acc += s_part[g2 * 256 + t];
        xfeat[i * 292 + t] = acc;
        if (t < 32) xfeat[i * 292 + 256 + t] = embed[si * 32 + t];
        if (t == 0) xfeat[i * 292 + 288] = tq[0];
    }
}

// ---------------------------------------------------------------------------
// K2 (R16) k_charge: charge MLP batched over AP=8 atoms/block (192 blocks).
// Each weight load cW1[k*64+o] is reused by 8 fma (vs 1 in the old fused
// phase 3), and total weight streaming drops 8x (192 vs 1536 blocks x 90KB).
// Summation order per atom matches R13 exactly (72/72/72/73 k-split).
// rsum: one f64 atomicAdd per block (192 total — the R14 disaster was 2.36M
// f32 CAS atomics, not this).
// ---------------------------------------------------------------------------
__global__ __launch_bounds__(256) void k_charge(
    const float* __restrict__ xfeat,
    const float* __restrict__ cW1, const float* __restrict__ cb1,
    const float* __restrict__ cW2, const float* __restrict__ cb2,
    const float* __restrict__ cW3, const float* __restrict__ cb3,
    const float* __restrict__ charge_scale,
    float* __restrict__ raw, double* __restrict__ rsum)
{
    __shared__ float s_xx[AP][292];     // 9.3 KB
    __shared__ float s_p[4][AP][64];    // 8 KB
    __shared__ float s_h[AP][64];       // 2 KB
    __shared__ float s_rawl[AP];

    const int t = threadIdx.x;
    const int a0 = blockIdx.x * AP;
    const int g3 = t >> 6, o = t & 63;

    #pragma unroll
    for (int a = 0; a < AP; a++)
        for (int e = t; e < 289; e += 256)
            s_xx[a][e] = xfeat[(a0 + a) * 292 + e];
    __syncthreads();

    // layer 1: K split 72/72/72/73 (R13 order), 8-atom weight reuse
    {
        const int k0 = g3 * 72;
        const int k1 = (g3 == 3) ? 289 : (k0 + 72);
        float acc[AP] = {0.f,0.f,0.f,0.f,0.f,0.f,0.f,0.f};
        #pragma unroll 4
        for (int k = k0; k < k1; k++) {
            const float w = cW1[k * 64 + o];
            #pragma unroll
            for (int a = 0; a < AP; a++) acc[a] += s_xx[a][k] * w;
        }
        #pragma unroll
        for (int a = 0; a < AP; a++) s_p[g3][a][o] = acc[a];
    }
    __syncthreads();
    #pragma unroll
    for (int aa = 0; aa < 2; aa++) {
        const int a = g3 * 2 + aa;
        const float v = cb1[o] + s_p[0][a][o] + s_p[1][a][o]
                      + s_p[2][a][o] + s_p[3][a][o];
        s_h[a][o] = silu_f(v);
    }
    __syncthreads();

    // layer 2: K split 16 per g3 (R13 order)
    {
        float acc[AP] = {0.f,0.f,0.f,0.f,0.f,0.f,0.f,0.f};
        #pragma unroll
        for (int kk = 0; kk < 16; kk++) {
            const int k = g3 * 16 + kk;
            const float w = cW2[k * 64 + o];
            #pragma unroll
            for (int a = 0; a < AP; a++) acc[a] += s_h[a][k] * w;
        }
        #pragma unroll
        for (int a = 0; a < AP; a++) s_p[g3][a][o] = acc[a];
    }
    __syncthreads();

    // layer 3 + raw (each wave g3 reduces its 2 atoms; o is the lane id)
    #pragma unroll
    for (int aa = 0; aa < 2; aa++) {
        const int a = g3 * 2 + aa;
        const float v = cb2[o] + s_p[0][a][o] + s_p[1][a][o]
                      + s_p[2][a][o] + s_p[3][a][o];
        float r = silu_f(v) * cW3[o];
        #pragma unroll
        for (int off = 32; off > 0; off >>= 1) r += __shfl_down(r, off);
        if (o == 0) {
            const float rawv = (r + cb3[0]) * charge_scale[0];
            raw[a0 + a] = rawv;
            s_rawl[a] = rawv;
        }
    }
    __syncthreads();
    if (t == 0) {
        double srp = 0.0;
        #pragma unroll
        for (int a = 0; a < AP; a++) srp += (double)s_rawl[a];
        atomicAdd(rsum, srp);
    }
}

// ---------------------------------------------------------------------------
// K3 (k_tail): byte-identical to R15 (R11-proven pair MLP on the matrix pipe
// + LR coulomb + ticket finale).
// ---------------------------------------------------------------------------
__global__ __launch_bounds__(256, 4) void k_tail(
    const int* __restrict__ species, const float* __restrict__ pos,
    const float* __restrict__ raw, const float* __restrict__ tq,
    const float* __restrict__ softening, const float* __restrict__ atom_bias,
    const float* __restrict__ coulomb_scale,
    const float* __restrict__ b2, const float* __restrict__ W3,
    const float* __restrict__ b3, const float* __restrict__ ctab,
    const short* __restrict__ bw1, const short* __restrict__ bw2,
    const unsigned int* __restrict__ pcount, const uint2* __restrict__ pdlist,
    const double* __restrict__ rsum,
    double* __restrict__ epp, double* __restrict__ elp,
    double* __restrict__ bias_part, unsigned int* __restrict__ done,
    float* __restrict__ out_energy, float* __restrict__ charges)
{
    __shared__ float s_tp[4][16 * 66];
    __shared__ float s_red[256];
    __shared__ double s_redd[256];
    __shared__ unsigned s_ticket;
    const int t = threadIdx.x;
    const int lane = t & 63;

    if (blockIdx.x < PAIR_B) {
        // ---------------- pair MLP on the matrix pipe ----------------
        const int wid = t >> 6;
        const int col = lane & 15;
        const int quad = lane >> 4;
        const short8* __restrict__ bw1v = (const short8*)bw1;
        const short8* __restrict__ bw2v = (const short8*)bw2;
        short8 w1f[4], w2f[8];
        #pragma unroll
        for (int t4 = 0; t4 < 4; t4++) w1f[t4] = bw1v[t4 * 64 + lane];
        #pragma unroll
        for (int q8 = 0; q8 < 8; q8++) w2f[q8] = bw2v[q8 * 64 + lane];
        float b2l[4], w3l[4];
        #pragma unroll
        for (int t4 = 0; t4 < 4; t4++) { b2l[t4] = b2[t4*16+col]; w3l[t4] = W3[t4*16+col]; }
        const float b3v = b3[0];
        const unsigned cnt = *pcount;
        float* tb = &s_tp[wid][0];

        float esum = 0.f;
        const unsigned wstep = PAIR_B * 4u;
        for (unsigned w = blockIdx.x * 4u + (unsigned)wid; w * 16u < cnt; w += wstep) {
            unsigned p_idx = w * 16u + (unsigned)col;
            const bool valid = p_idx < cnt;
            if (!valid) p_idx = cnt - 1;
            const uint2 pd = pdlist[p_idx];
            const int combo = (int)(pd.x >> 22);
            const float d = __uint_as_float(pd.y);
            const float cut = valid ? cut_f(d) : 0.f;
            if (lane < 16) esum += b3v * cut;

            short8 a1f;
            #pragma unroll
            for (int jj = 0; jj < 8; jj++) {
                const float ck = (float)(quad * 8 + jj) * (CUTOFF_R / 31.f);
                const float diff = d - ck;
                a1f[jj] = f2bf(__expf(-4.f * diff * diff));
            }

            int cmb[4]; float cutr[4];
            #pragma unroll
            for (int r = 0; r < 4; r++) {
                const int p = quad * 4 + r;
                cmb[r]  = __shfl(combo, p);
                cutr[r] = __shfl(cut, p);
            }

            float4v acc[4];
            #pragma unroll
            for (int t4 = 0; t4 < 4; t4++) {
                #pragma unroll
                for (int r = 0; r < 4; r++)
                    acc[t4][r] = ctab[cmb[r] * HID + t4 * 16 + col];
            }
            #pragma unroll
            for (int t4 = 0; t4 < 4; t4++)
                acc[t4] = __builtin_amdgcn_mfma_f32_16x16x32_bf16(a1f, w1f[t4], acc[t4], 0, 0, 0);

            #pragma unroll
            for (int t4 = 0; t4 < 4; t4++) {
                #pragma unroll
                for (int r = 0; r < 4; r++)
                    tb[(quad * 4 + r) * 66 + t4 * 16 + col] = silu_f(acc[t4][r]);
            }
            short8 a2f[2];
            #pragma unroll
            for (int c = 0; c < 2; c++) {
                #pragma unroll
                for (int jj = 0; jj < 8; jj++)
                    a2f[c][jj] = f2bf(tb[col * 66 + c * 32 + quad * 8 + jj]);
            }

            float4v acc2[4];
            #pragma unroll
            for (int t4 = 0; t4 < 4; t4++) {
                acc2[t4][0] = b2l[t4]; acc2[t4][1] = b2l[t4];
                acc2[t4][2] = b2l[t4]; acc2[t4][3] = b2l[t4];
            }
            #pragma unroll
            for (int c = 0; c < 2; c++) {
                #pragma unroll
                for (int t4 = 0; t4 < 4; t4++)
                    acc2[t4] = __builtin_amdgcn_mfma_f32_16x16x32_bf16(a2f[c], w2f[c*4+t4], acc2[t4], 0, 0, 0);
            }

            #pragma unroll
            for (int r = 0; r < 4; r++) {
                float part = 0.f;
                #pragma unroll
                for (int t4 = 0; t4 < 4; t4++) part += silu_f(acc2[t4][r]) * w3l[t4];
                esum += part * cutr[r];
            }
        }

        s_red[t] = esum;
        __syncthreads();
        for (int s = 128; s > 0; s >>= 1) { if (t < s) s_red[t] += s_red[t + s]; __syncthreads(); }
        if (t == 0)   // uncontended coherent store (slot is poisoned -> must write)
            atomicExch((unsigned long long*)&epp[blockIdx.x],
                       (unsigned long long)__double_as_longlong((double)s_red[0]));
    } else {
        // ---------------- LR coulomb + charges (+bias on first) -------
        const int b = blockIdx.x - PAIR_B;      // 0..255
        const float mean = (float)(rsum[0] / (double)NATOMS);
        const float add = tq[0] / (float)NATOMS;

        if (b == 0) {
            float acc = 0.f;
            for (int idx = t; idx < NATOMS; idx += 256) acc += atom_bias[species[idx]];
            s_red[t] = acc;
            __syncthreads();
            for (int s = 128; s > 0; s >>= 1) { if (t < s) s_red[t] += s_red[t + s]; __syncthreads(); }
            if (t == 0)
                atomicExch((unsigned long long*)bias_part,
                           (unsigned long long)__double_as_longlong((double)s_red[0]));
            __syncthreads();
        }

        const int gid = b * 256 + t;
        if (gid < NATOMS) charges[gid] = raw[gid] - mean + add;

        const float sr = softening[0];
        const float sp = ((sr > 20.f) ? sr : log1pf(__expf(sr))) + 0.001f;
        const float sp2 = sp * sp;
        float acc = 0.f;
        for (int i = b; i < NATOMS; i += 256) {
            const float xi = pos[3*i+0], yi = pos[3*i+1], zi = pos[3*i+2];
            const float qi = raw[i] - mean + add;
            for (int j = i + 1 + t; j < NATOMS; j += 256) {
                const float dx = xi - pos[3*j+0];
                const float dy = yi - pos[3*j+1];
                const float dz = zi - pos[3*j+2];
                const float d2 = dx*dx + dy*dy + dz*dz + 1e-12f;
                const float qj = raw[j] - mean + add;
                acc += qi * qj * rsqrtf(d2 + sp2);
            }
        }
        s_red[t] = acc;
        __syncthreads();
        for (int s = 128; s > 0; s >>= 1) { if (t < s) s_red[t] += s_red[t + s]; __syncthreads(); }
        if (t == 0)
            atomicExch((unsigned long long*)&elp[b],
                       (unsigned long long)__double_as_longlong((double)s_red[0]));
    }

    // ---------------- ticket finale (winner block sums partials) -----
    if (t == 0) {
        __threadfence();
        s_ticket = atomicAdd(done, 1u);
    }
    __syncthreads();
    if (s_ticket == (unsigned)TAIL_GRID - 1u) {
        __threadfence();
        const double cs = (double)coulomb_scale[0];
        double acc = 0.0;
        for (int idx = t; idx < PAIR_B; idx += 256)
            acc += __longlong_as_double(
                (long long)atomicAdd((unsigned long long*)&epp[idx], 0ull));
        if (t < 256) {   // one elp slot per thread (256 slots)
            acc += cs * __longlong_as_double(
                (long long)atomicAdd((unsigned long long*)&elp[t], 0ull));
        }
        s_redd[t] = acc;
        __syncthreads();
        for (int s = 128; s > 0; s >>= 1) { if (t < s) s_redd[t] += s_redd[t + s]; __syncthreads(); }
        if (t == 0) {
            const double bd = __longlong_as_double(
                (long long)atomicAdd((unsigned long long*)bias_part, 0ull));
            out_energy[0] = (float)(s_redd[0] + bd);
        }
    }
}

// ---------------------------------------------------------------------------
// Workspace layout (R16):
//   [0,24)    header: rsum, bias_part, pcount, done   (memset 24B)
//   [64,..)   raw 6144 | ctab 16384 | bw1 4096 | bw2 8192 | epp 6144 |
//             elp 2048 | xfeat 1536*292*4 | pdlist (~1.4MB)
// ---------------------------------------------------------------------------
extern "C" void kernel_launch(void* const* d_in, const int* in_sizes, int n_in,
                              void* d_out, int out_size, void* d_ws, size_t ws_size,
                              hipStream_t stream) {
    const int*   species       = (const int*)d_in[0];
    const float* pos           = (const float*)d_in[1];
    const float* tq            = (const float*)d_in[2];
    const float* embed         = (const float*)d_in[3];
    const float* W1            = (const float*)d_in[4];
    const float* b1            = (const float*)d_in[5];
    const float* W2            = (const float*)d_in[6];
    const float* b2            = (const float*)d_in[7];
    const float* W3            = (const float*)d_in[8];
    const float* b3            = (const float*)d_in[9];
    const float* atom_bias     = (const float*)d_in[10];
    const float* cW1           = (const float*)d_in[11];
    const float* cb1           = (const float*)d_in[12];
    const float* cW2           = (const float*)d_in[13];
    const float* cb2           = (const float*)d_in[14];
    const float* cW3           = (const float*)d_in[15];
    const float* cb3           = (const float*)d_in[16];
    const float* charge_scale  = (const float*)d_in[17];
    const float* coulomb_scale = (const float*)d_in[18];
    const float* softening     = (const float*)d_in[19];

    char* ws = (char*)d_ws;
    double*   rsum      = (double*)(ws + 0);
    double*   bias_part = (double*)(ws + 8);
    unsigned* pcount    = (unsigned*)(ws + 16);
    unsigned* done      = (unsigned*)(ws + 20);
    float*    raw       = (float*)(ws + 64);        // 6144 B
    float*    ctab      = (float*)(ws + 8192);      // 16384 B
    short*    bw1       = (short*)(ws + 24576);     // 4096 B
    short*    bw2       = (short*)(ws + 28672);     // 8192 B
    double*   epp       = (double*)(ws + 36864);    // 768 * 8 = 6144 B
    double*   elp       = (double*)(ws + 43008);    // 256 * 8 = 2048 B
    float*    xfeat     = (float*)(ws + 49152);     // 1536*292*4 = 1794048 B
    uint2*    pdlist    = (uint2*)(ws + 1843200);   // ~1.4 MB

    float* out     = (float*)d_out;
    float* charges = out + 1;   // output layout: [energy, charges[1536]]

    hipMemsetAsync(d_ws, 0, 24, stream);  // rsum, bias_part, pcount, done

    k_nbr<<<NATOMS + PREP_BLOCKS, 256, 0, stream>>>(
        species, pos, tq, embed, W1, b1, W2,
        ctab, bw1, bw2, xfeat, pcount, pdlist);
    k_charge<<<CHG_BLOCKS, 256, 0, stream>>>(
        xfeat, cW1, cb1, cW2, cb2, cW3, cb3, charge_scale, raw, rsum);
    k_tail<<<TAIL_GRID, 256, 0, stream>>>(
        species, pos, raw, tq, softening, atom_bias, coulomb_scale,
        b2, W3, b3, ctab, bw1, bw2, pcount, pdlist, rsum,
        epp, elp, bias_part, done, out, charges);
}

// Round 4
// 168.190 us; speedup vs baseline: 1.0753x; 1.0753x over previous
//
#include <hip/hip_runtime.h>
#include <math.h>

#define NATOMS 1536
#define NSPEC 8
#define HID 64
#define NCEN 32
#define CUTOFF_R 5.0f
#define PI_F 3.14159265358979323846f
#define NBR_CAP 1024   // max in-cutoff neighbors per atom (~560 worst case here)
#define MAXP 576       // per-atom pair-segment capacity (j>i pairs <= total nbrs ~560)
#define PREP_BLOCKS 65
#define AP 8           // atoms per k_charge block
#define CHG_BLOCKS (NATOMS / AP)   // 192
#define PAIR_B NATOMS  // k_tail: one pair block per atom
#define TAIL_GRID (PAIR_B + 256)

typedef __attribute__((ext_vector_type(8))) short short8;   // 8 bf16
typedef __attribute__((ext_vector_type(4))) float float4v;  // MFMA C/D

__device__ __forceinline__ float silu_f(float x) {
    return x / (1.f + __expf(-x));
}
__device__ __forceinline__ short f2bf(float x) {   // RNE f32->bf16
    unsigned u = __float_as_uint(x);
    u += 0x7fffu + ((u >> 16) & 1u);
    return (short)(u >> 16);
}
__device__ __forceinline__ float cut_f(float d) {
    return 0.5f * (__cosf((PI_F / CUTOFF_R) * d) + 1.f);
}

// ---------------------------------------------------------------------------
// K1 (R17) k_nbr: R13-proven phases 1/1b/2, but ZERO global atomics.
// R16 ablation: k_nbr and k_tail BOTH ~40us with low VALU/MFMA/HBM and
// occupancy-invariance (R13 35%, R15 50%, same time). Common factor: each
// kernel's same-address device-atomic chain (1536 pcount + 1536 rsum in old
// k_local; 1024-ticket+exch in k_tail) at ~15ns/serialized RMW ~= the whole
// kernel time. Fix: pairs go to fixed per-atom segments pdlist[i*MAXP..]
// with plain-stored pnum[i]; kernel boundaries provide coherence for free.
// Blocks [1536,1601): prep (ctab, bw1, bw2) unchanged.
// ---------------------------------------------------------------------------
__global__ __launch_bounds__(256) void k_nbr(
    const int* __restrict__ species, const float* __restrict__ pos,
    const float* __restrict__ tq, const float* __restrict__ embed,
    const float* __restrict__ W1, const float* __restrict__ b1,
    const float* __restrict__ W2,
    float* __restrict__ ctab, short* __restrict__ bw1, short* __restrict__ bw2,
    float* __restrict__ xfeat,
    unsigned int* __restrict__ pnum, uint2* __restrict__ pdlist)
{
    __shared__ float2 dc_l[NBR_CAP];            // 8 KB  (d, cut)
    __shared__ unsigned short spj_l[NBR_CAP];   // 2 KB  (species<<11 | j)
    __shared__ unsigned short pj_l[NBR_CAP];    // 2 KB  (neighbor-list index)
    __shared__ float s_part[8 * 256];           // 8 KB  (bucket partials)
    __shared__ unsigned n_cnt, p_cnt;

    const int t = threadIdx.x;

    // ---------------- prep blocks ----------------
    if (blockIdx.x >= NATOMS) {
        const int b = blockIdx.x - NATOMS;
        if (b < 64) {
            if (t < 64) {
                const int c = b;                  // combo = si*8+sj
                const int si2 = c >> 3, sj2 = c & 7;
                const int o = t;
                float acc = b1[o];
                #pragma unroll 4
                for (int k = 0; k < 32; k++) {
                    const float a = embed[si2 * 32 + k];
                    const float bb = embed[sj2 * 32 + k];
                    acc += (a + bb) * W1[(32 + k) * HID + o];
                    acc += (a * bb) * W1[(64 + k) * HID + o];
                }
                ctab[c * HID + o] = acc;
            }
        } else {
            for (int e = t; e < 2048; e += 256) {
                const int tile = e >> 9, L = (e >> 3) & 63, j = e & 7;
                const int k = (L >> 4) * 8 + j;
                const int n = tile * 16 + (L & 15);
                bw1[e] = f2bf(W1[k * HID + n]);
            }
            for (int e = t; e < 4096; e += 256) {
                const int ct = e >> 9, L = (e >> 3) & 63, j = e & 7;
                const int c = ct >> 2, tile = ct & 3;
                const int k = c * 32 + (L >> 4) * 8 + j;
                const int n = tile * 16 + (L & 15);
                bw2[e] = f2bf(W2[k * HID + n]);
            }
        }
        return;
    }

    const int i = blockIdx.x;
    const int lane = t & 63;
    if (t == 0) { n_cnt = 0u; p_cnt = 0u; }
    __syncthreads();

    const float xi = pos[3*i+0], yi = pos[3*i+1], zi = pos[3*i+2];
    const int si = species[i];

    // ---- phase 1: neighbor compaction ----
    #pragma unroll
    for (int j0 = 0; j0 < NATOMS; j0 += 256) {
        const int j = j0 + t;
        const float dx = xi - pos[3*j+0];
        const float dy = yi - pos[3*j+1];
        const float dz = zi - pos[3*j+2];
        const float d = sqrtf(dx*dx + dy*dy + dz*dz + 1e-12f);
        const bool within = (d < CUTOFF_R) && (j != i);
        const unsigned long long m = __ballot((int)within);
        if (within) {
            const unsigned prefix = (unsigned)__popcll(m & ((1ull << lane) - 1ull));
            unsigned base = 0;
            if (prefix == 0) base = atomicAdd(&n_cnt, (unsigned)__popcll(m));
            base = (unsigned)__builtin_amdgcn_readfirstlane((int)base);
            const unsigned ofs = base + prefix;
            if (ofs < NBR_CAP) {
                dc_l[ofs] = make_float2(d, cut_f(d));
                spj_l[ofs] = (unsigned short)((species[j] << 11) | j);
            }
        }
    }
    __syncthreads();
    const unsigned cnt = (n_cnt < NBR_CAP) ? n_cnt : NBR_CAP;

    // ---- phase 1b: pair list (j > i), store neighbor-list index ----
    for (unsigned n0 = 0; n0 < cnt; n0 += 256) {
        const unsigned n = n0 + (unsigned)t;
        bool app = false;
        if (n < cnt) app = ((int)(spj_l[n] & 2047u) > i);
        const unsigned long long m = __ballot((int)app);
        if (app) {
            const unsigned prefix = (unsigned)__popcll(m & ((1ull << lane) - 1ull));
            unsigned base = 0;
            if (prefix == 0) base = atomicAdd(&p_cnt, (unsigned)__popcll(m));
            base = (unsigned)__builtin_amdgcn_readfirstlane((int)base);
            pj_l[base + prefix] = (unsigned short)n;
        }
    }
    __syncthreads();
    {
        const unsigned pc = (p_cnt < MAXP) ? p_cnt : MAXP;
        for (unsigned idx = (unsigned)t; idx < pc; idx += 256) {
            const unsigned n = pj_l[idx];
            const unsigned w = spj_l[n];
            const unsigned jj = w & 2047u, spj = w >> 11;
            uint2 pd;
            pd.x = (((unsigned)si * 8u + spj) << 22) | ((unsigned)i << 11) | jj;
            pd.y = __float_as_uint(dc_l[n].x);
            pdlist[i * MAXP + idx] = pd;
        }
        if (t == 0) pnum[i] = pc;
    }

    // ---- phase 2: register-bucket basis accumulation (R8/R11-proven) ----
    {
        const int k = t & 31, gg = t >> 5;
        const float ck = (float)k * (CUTOFF_R / 31.f);
        float f0=0.f,f1=0.f,f2=0.f,f3=0.f,f4=0.f,f5=0.f,f6=0.f,f7=0.f;
        #pragma unroll 2
        for (unsigned n = (unsigned)gg; n < cnt; n += 8) {
            const float2 dc = dc_l[n];
            const float diff = dc.x - ck;
            const float v = __expf(-4.f * diff * diff) * dc.y;
            const int sp = (int)(spj_l[n] >> 11);
            f0 += (sp == 0) ? v : 0.f;
            f1 += (sp == 1) ? v : 0.f;
            f2 += (sp == 2) ? v : 0.f;
            f3 += (sp == 3) ? v : 0.f;
            f4 += (sp == 4) ? v : 0.f;
            f5 += (sp == 5) ? v : 0.f;
            f6 += (sp == 6) ? v : 0.f;
            f7 += (sp == 7) ? v : 0.f;
        }
        float* sp_g = &s_part[gg * 256 + k];
        sp_g[0*32] = f0; sp_g[1*32] = f1; sp_g[2*32] = f2; sp_g[3*32] = f3;
        sp_g[4*32] = f4; sp_g[5*32] = f5; sp_g[6*32] = f6; sp_g[7*32] = f7;
    }
    __syncthreads();
    {
        float acc = 0.f;
        #pragma unroll
        for (int g2 = 0; g2 < 8; g2++) acc += s_part[g2 * 256 + t];
        xfeat[i * 292 + t] = acc;
        if (t < 32) xfeat[i * 292 + 256 + t] = embed[si * 32 + t];
        if (t == 0) xfeat[i * 292 + 288] = tq[0];
    }
}

// ---------------------------------------------------------------------------
// K2 (R16-proven) k_charge: charge MLP batched over AP=8 atoms/block.
// R17: rsum atomic -> plain per-block partial store rpart[blockIdx].
// ---------------------------------------------------------------------------
__global__ __launch_bounds__(256) void k_charge(
    const float* __restrict__ xfeat,
    const float* __restrict__ cW1, const float* __restrict__ cb1,
    const float* __restrict__ cW2, const float* __restrict__ cb2,
    const float* __restrict__ cW3, const float* __restrict__ cb3,
    const float* __restrict__ charge_scale,
    float* __restrict__ raw, double* __restrict__ rpart)
{
    __shared__ float s_xx[AP][292];     // 9.3 KB
    __shared__ float s_p[4][AP][64];    // 8 KB
    __shared__ float s_h[AP][64];       // 2 KB
    __shared__ float s_rawl[AP];

    const int t = threadIdx.x;
    const int a0 = blockIdx.x * AP;
    const int g3 = t >> 6, o = t & 63;

    #pragma unroll
    for (int a = 0; a < AP; a++)
        for (int e = t; e < 289; e += 256)
            s_xx[a][e] = xfeat[(a0 + a) * 292 + e];
    __syncthreads();

    // layer 1: K split 72/72/72/73 (R13 order), 8-atom weight reuse
    {
        const int k0 = g3 * 72;
        const int k1 = (g3 == 3) ? 289 : (k0 + 72);
        float acc[AP] = {0.f,0.f,0.f,0.f,0.f,0.f,0.f,0.f};
        #pragma unroll 4
        for (int k = k0; k < k1; k++) {
            const float w = cW1[k * 64 + o];
            #pragma unroll
            for (int a = 0; a < AP; a++) acc[a] += s_xx[a][k] * w;
        }
        #pragma unroll
        for (int a = 0; a < AP; a++) s_p[g3][a][o] = acc[a];
    }
    __syncthreads();
    #pragma unroll
    for (int aa = 0; aa < 2; aa++) {
        const int a = g3 * 2 + aa;
        const float v = cb1[o] + s_p[0][a][o] + s_p[1][a][o]
                      + s_p[2][a][o] + s_p[3][a][o];
        s_h[a][o] = silu_f(v);
    }
    __syncthreads();

    // layer 2: K split 16 per g3 (R13 order)
    {
        float acc[AP] = {0.f,0.f,0.f,0.f,0.f,0.f,0.f,0.f};
        #pragma unroll
        for (int kk = 0; kk < 16; kk++) {
            const int k = g3 * 16 + kk;
            const float w = cW2[k * 64 + o];
            #pragma unroll
            for (int a = 0; a < AP; a++) acc[a] += s_h[a][k] * w;
        }
        #pragma unroll
        for (int a = 0; a < AP; a++) s_p[g3][a][o] = acc[a];
    }
    __syncthreads();

    // layer 3 + raw (each wave g3 reduces its 2 atoms; o is the lane id)
    #pragma unroll
    for (int aa = 0; aa < 2; aa++) {
        const int a = g3 * 2 + aa;
        const float v = cb2[o] + s_p[0][a][o] + s_p[1][a][o]
                      + s_p[2][a][o] + s_p[3][a][o];
        float r = silu_f(v) * cW3[o];
        #pragma unroll
        for (int off = 32; off > 0; off >>= 1) r += __shfl_down(r, off);
        if (o == 0) {
            const float rawv = (r + cb3[0]) * charge_scale[0];
            raw[a0 + a] = rawv;
            s_rawl[a] = rawv;
        }
    }
    __syncthreads();
    if (t == 0) {
        double srp = 0.0;
        #pragma unroll
        for (int a = 0; a < AP; a++) srp += (double)s_rawl[a];
        rpart[blockIdx.x] = srp;     // plain store, coherent at kernel boundary
    }
}

// ---------------------------------------------------------------------------
// K3 (R17) k_tail: pair MLP per-atom (blocks 0..1535: atom a's segment,
// 4 waves stride 4 over its tiles; ctab gathers now single-row -> L1-hit).
// Blocks 1536..1791: LR coulomb + charges (mean computed from rpart[192]).
// ALL results via plain stores (epp[a], elp[b]); ticket finale & threadfence
// chains removed -> k_final reads them after the kernel boundary.
// ---------------------------------------------------------------------------
__global__ __launch_bounds__(256, 4) void k_tail(
    const float* __restrict__ pos,
    const float* __restrict__ raw, const float* __restrict__ tq,
    const float* __restrict__ softening,
    const float* __restrict__ b2, const float* __restrict__ W3,
    const float* __restrict__ b3, const float* __restrict__ ctab,
    const short* __restrict__ bw1, const short* __restrict__ bw2,
    const unsigned int* __restrict__ pnum, const uint2* __restrict__ pdlist,
    const double* __restrict__ rpart,
    double* __restrict__ epp, double* __restrict__ elp,
    float* __restrict__ charges)
{
    __shared__ float s_tp[4][16 * 66];
    __shared__ float s_red[256];
    const int t = threadIdx.x;
    const int lane = t & 63;

    if (blockIdx.x < PAIR_B) {
        // ---------------- pair MLP on the matrix pipe ----------------
        const int a = blockIdx.x;
        const int wid = t >> 6;
        const int col = lane & 15;
        const int quad = lane >> 4;
        const unsigned pn = pnum[a];
        float esum = 0.f;

        if (pn > 0) {
            const short8* __restrict__ bw1v = (const short8*)bw1;
            const short8* __restrict__ bw2v = (const short8*)bw2;
            short8 w1f[4], w2f[8];
            #pragma unroll
            for (int t4 = 0; t4 < 4; t4++) w1f[t4] = bw1v[t4 * 64 + lane];
            #pragma unroll
            for (int q8 = 0; q8 < 8; q8++) w2f[q8] = bw2v[q8 * 64 + lane];
            float b2l[4], w3l[4];
            #pragma unroll
            for (int t4 = 0; t4 < 4; t4++) { b2l[t4] = b2[t4*16+col]; w3l[t4] = W3[t4*16+col]; }
            const float b3v = b3[0];
            const uint2* __restrict__ seg = pdlist + (size_t)a * MAXP;
            float* tb = &s_tp[wid][0];

            for (unsigned w = (unsigned)wid; w * 16u < pn; w += 4u) {
                unsigned p_idx = w * 16u + (unsigned)col;
                const bool valid = p_idx < pn;
                if (!valid) p_idx = pn - 1;
                const uint2 pd = seg[p_idx];
                const int combo = (int)(pd.x >> 22);
                const float d = __uint_as_float(pd.y);
                const float cut = valid ? cut_f(d) : 0.f;
                if (lane < 16) esum += b3v * cut;

                short8 a1f;
                #pragma unroll
                for (int jj = 0; jj < 8; jj++) {
                    const float ck = (float)(quad * 8 + jj) * (CUTOFF_R / 31.f);
                    const float diff = d - ck;
                    a1f[jj] = f2bf(__expf(-4.f * diff * diff));
                }

                int cmb[4]; float cutr[4];
                #pragma unroll
                for (int r = 0; r < 4; r++) {
                    const int p = quad * 4 + r;
                    cmb[r]  = __shfl(combo, p);
                    cutr[r] = __shfl(cut, p);
                }

                float4v acc[4];
                #pragma unroll
                for (int t4 = 0; t4 < 4; t4++) {
                    #pragma unroll
                    for (int r = 0; r < 4; r++)
                        acc[t4][r] = ctab[cmb[r] * HID + t4 * 16 + col];
                }
                #pragma unroll
                for (int t4 = 0; t4 < 4; t4++)
                    acc[t4] = __builtin_amdgcn_mfma_f32_16x16x32_bf16(a1f, w1f[t4], acc[t4], 0, 0, 0);

                #pragma unroll
                for (int t4 = 0; t4 < 4; t4++) {
                    #pragma unroll
                    for (int r = 0; r < 4; r++)
                        tb[(quad * 4 + r) * 66 + t4 * 16 + col] = silu_f(acc[t4][r]);
                }
                short8 a2f[2];
                #pragma unroll
                for (int c = 0; c < 2; c++) {
                    #pragma unroll
                    for (int jj = 0; jj < 8; jj++)
                        a2f[c][jj] = f2bf(tb[col * 66 + c * 32 + quad * 8 + jj]);
                }

                float4v acc2[4];
                #pragma unroll
                for (int t4 = 0; t4 < 4; t4++) {
                    acc2[t4][0] = b2l[t4]; acc2[t4][1] = b2l[t4];
                    acc2[t4][2] = b2l[t4]; acc2[t4][3] = b2l[t4];
                }
                #pragma unroll
                for (int c = 0; c < 2; c++) {
                    #pragma unroll
                    for (int t4 = 0; t4 < 4; t4++)
                        acc2[t4] = __builtin_amdgcn_mfma_f32_16x16x32_bf16(a2f[c], w2f[c*4+t4], acc2[t4], 0, 0, 0);
                }

                #pragma unroll
                for (int r = 0; r < 4; r++) {
                    float part = 0.f;
                    #pragma unroll
                    for (int t4 = 0; t4 < 4; t4++) part += silu_f(acc2[t4][r]) * w3l[t4];
                    esum += part * cutr[r];
                }
            }
        }

        s_red[t] = esum;
        __syncthreads();
        for (int s = 128; s > 0; s >>= 1) { if (t < s) s_red[t] += s_red[t + s]; __syncthreads(); }
        if (t == 0) epp[a] = (double)s_red[0];   // plain store
    } else {
        // ---------------- LR coulomb + charges ----------------
        const int b = blockIdx.x - PAIR_B;      // 0..255

        // deterministic mean from k_charge partials (f64, fixed order)
        double rs = 0.0;
        for (int k = 0; k < CHG_BLOCKS; k++) rs += rpart[k];
        const float mean = (float)(rs / (double)NATOMS);
        const float add = tq[0] / (float)NATOMS;

        const int gid = b * 256 + t;
        if (gid < NATOMS) charges[gid] = raw[gid] - mean + add;

        const float sr = softening[0];
        const float sp = ((sr > 20.f) ? sr : log1pf(__expf(sr))) + 0.001f;
        const float sp2 = sp * sp;
        float acc = 0.f;
        for (int i = b; i < NATOMS; i += 256) {
            const float xi = pos[3*i+0], yi = pos[3*i+1], zi = pos[3*i+2];
            const float qi = raw[i] - mean + add;
            for (int j = i + 1 + t; j < NATOMS; j += 256) {
                const float dx = xi - pos[3*j+0];
                const float dy = yi - pos[3*j+1];
                const float dz = zi - pos[3*j+2];
                const float d2 = dx*dx + dy*dy + dz*dz + 1e-12f;
                const float qj = raw[j] - mean + add;
                acc += qi * qj * rsqrtf(d2 + sp2);
            }
        }
        s_red[t] = acc;
        __syncthreads();
        for (int s = 128; s > 0; s >>= 1) { if (t < s) s_red[t] += s_red[t + s]; __syncthreads(); }
        if (t == 0) elp[b] = (double)s_red[0];   // plain store
    }
}

// ---------------------------------------------------------------------------
// K4 (R17) k_final: one block sums epp[1536] + cs*elp[256] + species bias.
// Replaces the in-kernel ticket finale (and its 1024-op atomic chain).
// ---------------------------------------------------------------------------
__global__ __launch_bounds__(256) void k_final(
    const int* __restrict__ species, const float* __restrict__ atom_bias,
    const float* __restrict__ coulomb_scale,
    const double* __restrict__ epp, const double* __restrict__ elp,
    float* __restrict__ out_energy)
{
    __shared__ float s_red[256];
    __shared__ double s_redd[256];
    const int t = threadIdx.x;

    float bacc = 0.f;
    for (int idx = t; idx < NATOMS; idx += 256) bacc += atom_bias[species[idx]];
    s_red[t] = bacc;
    __syncthreads();
    for (int s = 128; s > 0; s >>= 1) { if (t < s) s_red[t] += s_red[t + s]; __syncthreads(); }

    const double cs = (double)coulomb_scale[0];
    double acc = 0.0;
    for (int idx = t; idx < PAIR_B; idx += 256) acc += epp[idx];
    acc += cs * elp[t];
    s_redd[t] = acc;
    __syncthreads();
    for (int s = 128; s > 0; s >>= 1) { if (t < s) s_redd[t] += s_redd[t + s]; __syncthreads(); }
    if (t == 0) out_energy[0] = (float)(s_redd[0] + (double)s_red[0]);
}

// ---------------------------------------------------------------------------
// Workspace layout (R17) — NO memset needed: every slot read is written
// unconditionally each iteration (rpart by 192 blocks, pnum/epp by 1536,
// elp by 256, pdlist only read in [0,pnum[i]) ).
//   [0,1536)            rpart[192] f64
//   [2048,8192)         raw[1536] f32
//   [8192,24576)        ctab
//   [24576,28672)       bw1
//   [28672,36864)       bw2
//   [36864,49152)       epp[1536] f64
//   [49152,51200)       elp[256] f64
//   [51200,57344)       pnum[1536] u32
//   [57344,1851392)     xfeat[1536*292] f32
//   [1851392,8929280)   pdlist[1536*576] uint2  (~6.8 MB)
// ---------------------------------------------------------------------------
extern "C" void kernel_launch(void* const* d_in, const int* in_sizes, int n_in,
                              void* d_out, int out_size, void* d_ws, size_t ws_size,
                              hipStream_t stream) {
    const int*   species       = (const int*)d_in[0];
    const float* pos           = (const float*)d_in[1];
    const float* tq            = (const float*)d_in[2];
    const float* embed         = (const float*)d_in[3];
    const float* W1            = (const float*)d_in[4];
    const float* b1            = (const float*)d_in[5];
    const float* W2            = (const float*)d_in[6];
    const float* b2            = (const float*)d_in[7];
    const float* W3            = (const float*)d_in[8];
    const float* b3            = (const float*)d_in[9];
    const float* atom_bias     = (const float*)d_in[10];
    const float* cW1           = (const float*)d_in[11];
    const float* cb1           = (const float*)d_in[12];
    const float* cW2           = (const float*)d_in[13];
    const float* cb2           = (const float*)d_in[14];
    const float* cW3           = (const float*)d_in[15];
    const float* cb3           = (const float*)d_in[16];
    const float* charge_scale  = (const float*)d_in[17];
    const float* coulomb_scale = (const float*)d_in[18];
    const float* softening     = (const float*)d_in[19];

    char* ws = (char*)d_ws;
    double*   rpart  = (double*)(ws + 0);          // 192*8
    float*    raw    = (float*)(ws + 2048);        // 6144
    float*    ctab   = (float*)(ws + 8192);        // 16384
    short*    bw1    = (short*)(ws + 24576);       // 4096
    short*    bw2    = (short*)(ws + 28672);       // 8192
    double*   epp    = (double*)(ws + 36864);      // 1536*8
    double*   elp    = (double*)(ws + 49152);      // 256*8
    unsigned* pnum   = (unsigned*)(ws + 51200);    // 1536*4
    float*    xfeat  = (float*)(ws + 57344);       // 1536*292*4
    uint2*    pdlist = (uint2*)(ws + 1851392);     // 1536*576*8

    float* out     = (float*)d_out;
    float* charges = out + 1;   // output layout: [energy, charges[1536]]

    k_nbr<<<NATOMS + PREP_BLOCKS, 256, 0, stream>>>(
        species, pos, tq, embed, W1, b1, W2,
        ctab, bw1, bw2, xfeat, pnum, pdlist);
    k_charge<<<CHG_BLOCKS, 256, 0, stream>>>(
        xfeat, cW1, cb1, cW2, cb2, cW3, cb3, charge_scale, raw, rpart);
    k_tail<<<TAIL_GRID, 256, 0, stream>>>(
        pos, raw, tq, softening,
        b2, W3, b3, ctab, bw1, bw2, pnum, pdlist, rpart,
        epp, elp, charges);
    k_final<<<1, 256, 0, stream>>>(
        species, atom_bias, coulomb_scale, epp, elp, out);
}

// Round 6
// 144.153 us; speedup vs baseline: 1.2546x; 1.1667x over previous
//
#include <hip/hip_runtime.h>
#include <math.h>

#define NATOMS 1536
#define NSPEC 8
#define HID 64
#define NCEN 32
#define CUTOFF_R 5.0f
#define PI_F 3.14159265358979323846f
#define NBR_CAP 1024   // max in-cutoff neighbors per atom (~560 worst case here)
#define MAXP 576       // per-atom pair-segment capacity (j>i pairs <= total nbrs)
#define PREP_BLOCKS 65
#define PAIR_B NATOMS  // k_pairlr: one pair block per atom
#define TAIL_GRID (PAIR_B + 256)

typedef __attribute__((ext_vector_type(8))) short short8;   // 8 bf16
typedef __attribute__((ext_vector_type(4))) float float4v;  // MFMA C/D

__device__ __forceinline__ float silu_f(float x) {
    return x / (1.f + __expf(-x));
}
__device__ __forceinline__ short f2bf(float x) {   // RNE f32->bf16
    unsigned u = __float_as_uint(x);
    u += 0x7fffu + ((u >> 16) & 1u);
    return (short)(u >> 16);
}
__device__ __forceinline__ float cut_f(float d) {
    return 0.5f * (__cosf((PI_F / CUTOFF_R) * d) + 1.f);
}

// ---------------------------------------------------------------------------
// K1 (R18) k_one: phases 1+1b FUSED (pairs emitted straight from registers
// during the neighbor scan via a second ballot -> one fewer barrier pass,
// pj_l deleted), phase 2 (R8/R11-proven register buckets), and the R13-exact
// charge MLP fused back in (R16 ablation: ~4us marginal; saves a dispatch
// and the xfeat global round-trip). ZERO global atomics anywhere (R16/R17
// lesson: same-address device-atomic chains were the invariant ~40us).
// raw[i] is a plain store; kernel boundary provides coherence.
// Blocks [1536,1601): prep (ctab, bw1, bw2) unchanged.
// [R18b: byte-identical resubmit — R18 bench died to container acquisition,
// not to the kernel; static audit found no OOB/hang/capture hazard.]
// ---------------------------------------------------------------------------
__global__ __launch_bounds__(256) void k_one(
    const int* __restrict__ species, const float* __restrict__ pos,
    const float* __restrict__ tq, const float* __restrict__ embed,
    const float* __restrict__ cW1, const float* __restrict__ cb1,
    const float* __restrict__ cW2, const float* __restrict__ cb2,
    const float* __restrict__ cW3, const float* __restrict__ cb3,
    const float* __restrict__ charge_scale,
    const float* __restrict__ W1, const float* __restrict__ b1,
    const float* __restrict__ W2,
    float* __restrict__ ctab, short* __restrict__ bw1, short* __restrict__ bw2,
    float* __restrict__ raw,
    unsigned int* __restrict__ pnum, uint2* __restrict__ pdlist)
{
    __shared__ float2 dc_l[NBR_CAP];            // 8 KB  (d, cut)
    __shared__ unsigned short spj_l[NBR_CAP];   // 2 KB  (species<<11 | j)
    __shared__ float s_part[8 * 256];           // 8 KB  (buckets, then partials)
    __shared__ float s_x[292];                  // feature vector
    __shared__ float s_h[64];
    __shared__ unsigned n_cnt, p_cnt;

    const int t = threadIdx.x;

    // ---------------- prep blocks ----------------
    if (blockIdx.x >= NATOMS) {
        const int b = blockIdx.x - NATOMS;
        if (b < 64) {
            if (t < 64) {
                const int c = b;                  // combo = si*8+sj
                const int si2 = c >> 3, sj2 = c & 7;
                const int o = t;
                float acc = b1[o];
                #pragma unroll 4
                for (int k = 0; k < 32; k++) {
                    const float a = embed[si2 * 32 + k];
                    const float bb = embed[sj2 * 32 + k];
                    acc += (a + bb) * W1[(32 + k) * HID + o];
                    acc += (a * bb) * W1[(64 + k) * HID + o];
                }
                ctab[c * HID + o] = acc;
            }
        } else {
            for (int e = t; e < 2048; e += 256) {
                const int tile = e >> 9, L = (e >> 3) & 63, j = e & 7;
                const int k = (L >> 4) * 8 + j;
                const int n = tile * 16 + (L & 15);
                bw1[e] = f2bf(W1[k * HID + n]);
            }
            for (int e = t; e < 4096; e += 256) {
                const int ct = e >> 9, L = (e >> 3) & 63, j = e & 7;
                const int c = ct >> 2, tile = ct & 3;
                const int k = c * 32 + (L >> 4) * 8 + j;
                const int n = tile * 16 + (L & 15);
                bw2[e] = f2bf(W2[k * HID + n]);
            }
        }
        return;
    }

    const int i = blockIdx.x;
    const int lane = t & 63;
    if (t == 0) { n_cnt = 0u; p_cnt = 0u; }
    __syncthreads();

    const float xi = pos[3*i+0], yi = pos[3*i+1], zi = pos[3*i+2];
    const int si = species[i];

    // ---- phase 1 (fused 1b): neighbor compaction + direct pair emission ----
    #pragma unroll
    for (int j0 = 0; j0 < NATOMS; j0 += 256) {
        const int j = j0 + t;
        const float dx = xi - pos[3*j+0];
        const float dy = yi - pos[3*j+1];
        const float dz = zi - pos[3*j+2];
        const float d = sqrtf(dx*dx + dy*dy + dz*dz + 1e-12f);
        const bool within = (d < CUTOFF_R) && (j != i);
        const bool pair   = within && (j > i);
        const unsigned long long m  = __ballot((int)within);
        const unsigned long long mp = __ballot((int)pair);
        int spj = 0;
        if (within) {
            spj = species[j];
            const unsigned prefix = (unsigned)__popcll(m & ((1ull << lane) - 1ull));
            unsigned base = 0;
            if (prefix == 0) base = atomicAdd(&n_cnt, (unsigned)__popcll(m));
            base = (unsigned)__builtin_amdgcn_readfirstlane((int)base);
            const unsigned ofs = base + prefix;
            if (ofs < NBR_CAP) {
                dc_l[ofs] = make_float2(d, cut_f(d));
                spj_l[ofs] = (unsigned short)((spj << 11) | j);
            }
        }
        if (pair) {
            const unsigned pprefix = (unsigned)__popcll(mp & ((1ull << lane) - 1ull));
            unsigned pbase = 0;
            if (pprefix == 0) pbase = atomicAdd(&p_cnt, (unsigned)__popcll(mp));
            pbase = (unsigned)__builtin_amdgcn_readfirstlane((int)pbase);
            const unsigned ofs = pbase + pprefix;
            if (ofs < MAXP) {
                uint2 pd;
                pd.x = (((unsigned)si * 8u + (unsigned)spj) << 22)
                     | ((unsigned)i << 11) | (unsigned)j;
                pd.y = __float_as_uint(d);
                pdlist[i * MAXP + ofs] = pd;
            }
        }
    }
    __syncthreads();
    const unsigned cnt = (n_cnt < NBR_CAP) ? n_cnt : NBR_CAP;
    if (t == 0) pnum[i] = (p_cnt < MAXP) ? p_cnt : MAXP;

    // ---- phase 2: register-bucket basis accumulation (R8/R11-proven) ----
    {
        const int k = t & 31, gg = t >> 5;
        const float ck = (float)k * (CUTOFF_R / 31.f);
        float f0=0.f,f1=0.f,f2=0.f,f3=0.f,f4=0.f,f5=0.f,f6=0.f,f7=0.f;
        #pragma unroll 2
        for (unsigned n = (unsigned)gg; n < cnt; n += 8) {
            const float2 dc = dc_l[n];
            const float diff = dc.x - ck;
            const float v = __expf(-4.f * diff * diff) * dc.y;
            const int sp = (int)(spj_l[n] >> 11);
            f0 += (sp == 0) ? v : 0.f;
            f1 += (sp == 1) ? v : 0.f;
            f2 += (sp == 2) ? v : 0.f;
            f3 += (sp == 3) ? v : 0.f;
            f4 += (sp == 4) ? v : 0.f;
            f5 += (sp == 5) ? v : 0.f;
            f6 += (sp == 6) ? v : 0.f;
            f7 += (sp == 7) ? v : 0.f;
        }
        float* sp_g = &s_part[gg * 256 + k];
        sp_g[0*32] = f0; sp_g[1*32] = f1; sp_g[2*32] = f2; sp_g[3*32] = f3;
        sp_g[4*32] = f4; sp_g[5*32] = f5; sp_g[6*32] = f6; sp_g[7*32] = f7;
    }
    __syncthreads();
    {
        float acc = 0.f;
        #pragma unroll
        for (int g2 = 0; g2 < 8; g2++) acc += s_part[g2 * 256 + t];
        s_x[t] = acc;
        if (t < 32) s_x[256 + t] = embed[si * 32 + t];
        if (t == 0) s_x[288] = tq[0];
    }
    __syncthreads();

    // ---- phase 3: charge MLP over s_x[289] (R13-exact orders) ----
    {
        const int g3 = t >> 6, o = t & 63;
        const int k0 = g3 * 72;
        const int k1 = (g3 == 3) ? 289 : (k0 + 72);
        float acc = 0.f;
        #pragma unroll 8
        for (int k = k0; k < k1; k++) acc += s_x[k] * cW1[k * 64 + o];
        s_part[g3 * 64 + o] = acc;
    }
    __syncthreads();
    if (t < 64) {
        const float a = cb1[t] + s_part[t] + s_part[64 + t]
                      + s_part[128 + t] + s_part[192 + t];
        s_h[t] = silu_f(a);
    }
    __syncthreads();
    {
        const int g3 = t >> 6, o = t & 63;
        float acc = 0.f;
        #pragma unroll
        for (int kk = 0; kk < 16; kk++) {
            const int k = g3 * 16 + kk;
            acc += s_h[k] * cW2[k * 64 + o];
        }
        s_part[g3 * 64 + o] = acc;
    }
    __syncthreads();
    if (t < 64) {
        const float a = cb2[t] + s_part[t] + s_part[64 + t]
                      + s_part[128 + t] + s_part[192 + t];
        float v = silu_f(a) * cW3[t];
        #pragma unroll
        for (int off = 32; off > 0; off >>= 1) v += __shfl_down(v, off);
        if (t == 0)
            raw[i] = (v + cb3[0]) * charge_scale[0];   // plain store, no atomic
    }
}

// ---------------------------------------------------------------------------
// K2 (R18) k_pairlr: blocks 0..1535 pair MLP per atom (R17-proven per-atom
// segments, ctab single-row L1-hit, plain epp stores). Blocks 1536..1791:
// LR coulomb + charges; each LR block computes the charge mean itself by a
// deterministic strided+tree f32 reduction over raw[1536] (L1-resident).
// No atomics, no tickets, no fences.
// ---------------------------------------------------------------------------
__global__ __launch_bounds__(256, 4) void k_pairlr(
    const float* __restrict__ pos,
    const float* __restrict__ raw, const float* __restrict__ tq,
    const float* __restrict__ softening,
    const float* __restrict__ b2, const float* __restrict__ W3,
    const float* __restrict__ b3, const float* __restrict__ ctab,
    const short* __restrict__ bw1, const short* __restrict__ bw2,
    const unsigned int* __restrict__ pnum, const uint2* __restrict__ pdlist,
    double* __restrict__ epp, double* __restrict__ elp,
    float* __restrict__ charges)
{
    __shared__ float s_tp[4][16 * 66];
    __shared__ float s_red[256];
    const int t = threadIdx.x;
    const int lane = t & 63;

    if (blockIdx.x < PAIR_B) {
        // ---------------- pair MLP on the matrix pipe ----------------
        const int a = blockIdx.x;
        const int wid = t >> 6;
        const int col = lane & 15;
        const int quad = lane >> 4;
        const unsigned pn = pnum[a];
        float esum = 0.f;

        if (pn > 0) {
            const short8* __restrict__ bw1v = (const short8*)bw1;
            const short8* __restrict__ bw2v = (const short8*)bw2;
            short8 w1f[4], w2f[8];
            #pragma unroll
            for (int t4 = 0; t4 < 4; t4++) w1f[t4] = bw1v[t4 * 64 + lane];
            #pragma unroll
            for (int q8 = 0; q8 < 8; q8++) w2f[q8] = bw2v[q8 * 64 + lane];
            float b2l[4], w3l[4];
            #pragma unroll
            for (int t4 = 0; t4 < 4; t4++) { b2l[t4] = b2[t4*16+col]; w3l[t4] = W3[t4*16+col]; }
            const float b3v = b3[0];
            const uint2* __restrict__ seg = pdlist + (size_t)a * MAXP;
            float* tb = &s_tp[wid][0];

            for (unsigned w = (unsigned)wid; w * 16u < pn; w += 4u) {
                unsigned p_idx = w * 16u + (unsigned)col;
                const bool valid = p_idx < pn;
                if (!valid) p_idx = pn - 1;
                const uint2 pd = seg[p_idx];
                const int combo = (int)(pd.x >> 22);
                const float d = __uint_as_float(pd.y);
                const float cut = valid ? cut_f(d) : 0.f;
                if (lane < 16) esum += b3v * cut;

                short8 a1f;
                #pragma unroll
                for (int jj = 0; jj < 8; jj++) {
                    const float ck = (float)(quad * 8 + jj) * (CUTOFF_R / 31.f);
                    const float diff = d - ck;
                    a1f[jj] = f2bf(__expf(-4.f * diff * diff));
                }

                int cmb[4]; float cutr[4];
                #pragma unroll
                for (int r = 0; r < 4; r++) {
                    const int p = quad * 4 + r;
                    cmb[r]  = __shfl(combo, p);
                    cutr[r] = __shfl(cut, p);
                }

                float4v acc[4];
                #pragma unroll
                for (int t4 = 0; t4 < 4; t4++) {
                    #pragma unroll
                    for (int r = 0; r < 4; r++)
                        acc[t4][r] = ctab[cmb[r] * HID + t4 * 16 + col];
                }
                #pragma unroll
                for (int t4 = 0; t4 < 4; t4++)
                    acc[t4] = __builtin_amdgcn_mfma_f32_16x16x32_bf16(a1f, w1f[t4], acc[t4], 0, 0, 0);

                #pragma unroll
                for (int t4 = 0; t4 < 4; t4++) {
                    #pragma unroll
                    for (int r = 0; r < 4; r++)
                        tb[(quad * 4 + r) * 66 + t4 * 16 + col] = silu_f(acc[t4][r]);
                }
                short8 a2f[2];
                #pragma unroll
                for (int c = 0; c < 2; c++) {
                    #pragma unroll
                    for (int jj = 0; jj < 8; jj++)
                        a2f[c][jj] = f2bf(tb[col * 66 + c * 32 + quad * 8 + jj]);
                }

                float4v acc2[4];
                #pragma unroll
                for (int t4 = 0; t4 < 4; t4++) {
                    acc2[t4][0] = b2l[t4]; acc2[t4][1] = b2l[t4];
                    acc2[t4][2] = b2l[t4]; acc2[t4][3] = b2l[t4];
                }
                #pragma unroll
                for (int c = 0; c < 2; c++) {
                    #pragma unroll
                    for (int t4 = 0; t4 < 4; t4++)
                        acc2[t4] = __builtin_amdgcn_mfma_f32_16x16x32_bf16(a2f[c], w2f[c*4+t4], acc2[t4], 0, 0, 0);
                }

                #pragma unroll
                for (int r = 0; r < 4; r++) {
                    float part = 0.f;
                    #pragma unroll
                    for (int t4 = 0; t4 < 4; t4++) part += silu_f(acc2[t4][r]) * w3l[t4];
                    esum += part * cutr[r];
                }
            }
        }

        s_red[t] = esum;
        __syncthreads();
        for (int s = 128; s > 0; s >>= 1) { if (t < s) s_red[t] += s_red[t + s]; __syncthreads(); }
        if (t == 0) epp[a] = (double)s_red[0];   // plain store
    } else {
        // ---------------- LR coulomb + charges ----------------
        const int b = blockIdx.x - PAIR_B;      // 0..255

        // deterministic mean over raw[1536] (same order in every LR block)
        float macc = 0.f;
        for (int idx = t; idx < NATOMS; idx += 256) macc += raw[idx];
        s_red[t] = macc;
        __syncthreads();
        for (int s = 128; s > 0; s >>= 1) { if (t < s) s_red[t] += s_red[t + s]; __syncthreads(); }
        const float mean = s_red[0] / (float)NATOMS;
        const float add = tq[0] / (float)NATOMS;
        __syncthreads();

        const int gid = b * 256 + t;
        if (gid < NATOMS) charges[gid] = raw[gid] - mean + add;

        const float sr = softening[0];
        const float sp = ((sr > 20.f) ? sr : log1pf(__expf(sr))) + 0.001f;
        const float sp2 = sp * sp;
        float acc = 0.f;
        for (int i = b; i < NATOMS; i += 256) {
            const float xi = pos[3*i+0], yi = pos[3*i+1], zi = pos[3*i+2];
            const float qi = raw[i] - mean + add;
            for (int j = i + 1 + t; j < NATOMS; j += 256) {
                const float dx = xi - pos[3*j+0];
                const float dy = yi - pos[3*j+1];
                const float dz = zi - pos[3*j+2];
                const float d2 = dx*dx + dy*dy + dz*dz + 1e-12f;
                const float qj = raw[j] - mean + add;
                acc += qi * qj * rsqrtf(d2 + sp2);
            }
        }
        s_red[t] = acc;
        __syncthreads();
        for (int s = 128; s > 0; s >>= 1) { if (t < s) s_red[t] += s_red[t + s]; __syncthreads(); }
        if (t == 0) elp[b] = (double)s_red[0];   // plain store
    }
}

// ---------------------------------------------------------------------------
// K3 (R17-proven) k_final: one block sums epp[1536] + cs*elp[256] + bias.
// ---------------------------------------------------------------------------
__global__ __launch_bounds__(256) void k_final(
    const int* __restrict__ species, const float* __restrict__ atom_bias,
    const float* __restrict__ coulomb_scale,
    const double* __restrict__ epp, const double* __restrict__ elp,
    float* __restrict__ out_energy)
{
    __shared__ float s_red[256];
    __shared__ double s_redd[256];
    const int t = threadIdx.x;

    float bacc = 0.f;
    for (int idx = t; idx < NATOMS; idx += 256) bacc += atom_bias[species[idx]];
    s_red[t] = bacc;
    __syncthreads();
    for (int s = 128; s > 0; s >>= 1) { if (t < s) s_red[t] += s_red[t + s]; __syncthreads(); }

    const double cs = (double)coulomb_scale[0];
    double acc = 0.0;
    for (int idx = t; idx < PAIR_B; idx += 256) acc += epp[idx];
    acc += cs * elp[t];
    s_redd[t] = acc;
    __syncthreads();
    for (int s = 128; s > 0; s >>= 1) { if (t < s) s_redd[t] += s_redd[t + s]; __syncthreads(); }
    if (t == 0) out_energy[0] = (float)(s_redd[0] + (double)s_red[0]);
}

// ---------------------------------------------------------------------------
// Workspace layout (R18) — NO memset, NO global atomics anywhere.
// Every slot read is written unconditionally each iteration:
//   raw by 1536 atom blocks, pnum/epp by 1536, elp by 256,
//   pdlist only read in [0,pnum[i]).
//   [64,6208)          raw[1536] f32
//   [8192,24576)       ctab
//   [24576,28672)      bw1
//   [28672,36864)      bw2
//   [36864,49152)      epp[1536] f64
//   [49152,51200)      elp[256] f64
//   [51200,57344)      pnum[1536] u32
//   [57344,7135232)    pdlist[1536*576] uint2 (~7 MB)
// ---------------------------------------------------------------------------
extern "C" void kernel_launch(void* const* d_in, const int* in_sizes, int n_in,
                              void* d_out, int out_size, void* d_ws, size_t ws_size,
                              hipStream_t stream) {
    const int*   species       = (const int*)d_in[0];
    const float* pos           = (const float*)d_in[1];
    const float* tq            = (const float*)d_in[2];
    const float* embed         = (const float*)d_in[3];
    const float* W1            = (const float*)d_in[4];
    const float* b1            = (const float*)d_in[5];
    const float* W2            = (const float*)d_in[6];
    const float* b2            = (const float*)d_in[7];
    const float* W3            = (const float*)d_in[8];
    const float* b3            = (const float*)d_in[9];
    const float* atom_bias     = (const float*)d_in[10];
    const float* cW1           = (const float*)d_in[11];
    const float* cb1           = (const float*)d_in[12];
    const float* cW2           = (const float*)d_in[13];
    const float* cb2           = (const float*)d_in[14];
    const float* cW3           = (const float*)d_in[15];
    const float* cb3           = (const float*)d_in[16];
    const float* charge_scale  = (const float*)d_in[17];
    const float* coulomb_scale = (const float*)d_in[18];
    const float* softening     = (const float*)d_in[19];

    char* ws = (char*)d_ws;
    float*    raw    = (float*)(ws + 64);          // 6144
    float*    ctab   = (float*)(ws + 8192);        // 16384
    short*    bw1    = (short*)(ws + 24576);       // 4096
    short*    bw2    = (short*)(ws + 28672);       // 8192
    double*   epp    = (double*)(ws + 36864);      // 1536*8
    double*   elp    = (double*)(ws + 49152);      // 256*8
    unsigned* pnum   = (unsigned*)(ws + 51200);    // 1536*4
    uint2*    pdlist = (uint2*)(ws + 57344);       // 1536*576*8

    float* out     = (float*)d_out;
    float* charges = out + 1;   // output layout: [energy, charges[1536]]

    k_one<<<NATOMS + PREP_BLOCKS, 256, 0, stream>>>(
        species, pos, tq, embed,
        cW1, cb1, cW2, cb2, cW3, cb3, charge_scale,
        W1, b1, W2, ctab, bw1, bw2,
        raw, pnum, pdlist);
    k_pairlr<<<TAIL_GRID, 256, 0, stream>>>(
        pos, raw, tq, softening,
        b2, W3, b3, ctab, bw1, bw2, pnum, pdlist,
        epp, elp, charges);
    k_final<<<1, 256, 0, stream>>>(
        species, atom_bias, coulomb_scale, epp, elp, out);
}